// Round 4
// baseline (114.465 us; speedup 1.0000x reference)
//
#include <hip/hip_runtime.h>
#include <hip/hip_bf16.h>
#include <cmath>

#define LATENTS 64
#define HID 64
#define IN_DIM 65
#define SLOPE 0.2f
#define FEPS 1e-8f
#define MB 64   // batch rows per block (16 per wave)

// ws layout (u32 units):
//  [0, 786432)           W0/W1/W2 frags: ((l*3+d)*2+ks)*4+ct, per-lane 8 u32 (hi4|lo4)
//  [W3OFF, +65536)       W3 frags: ((l*2+ks)*64+L)*8  (col0 = w3, cols 1-15 = 0)
//  [W65OFF, +4096)       w65[l][c] fp32 (W0 column 64)
#define W3OFF  786432u
#define W65OFF 851968u

typedef __attribute__((ext_vector_type(8))) short short8;
typedef __attribute__((ext_vector_type(4))) float f32x4;

__device__ __forceinline__ unsigned asu(float f){ return __builtin_bit_cast(unsigned, f); }
__device__ __forceinline__ float    asf(unsigned u){ return __builtin_bit_cast(float, u); }
__device__ __forceinline__ unsigned bfu(float f){
    return (unsigned)__builtin_bit_cast(unsigned short, __float2bfloat16(f));
}

// LDS addressing for bf16 [64][64] planes, XOR-swizzled for conflict-free b128 reads
__device__ __forceinline__ unsigned lds_byte(int r, int k){
    return (((unsigned)(r * 64 + k)) << 1) ^ (((unsigned)r & 7u) << 4);
}
__device__ __forceinline__ short8 frag16(const ushort* base, int r, int k0){
    return *(const short8*)((const char*)base + lds_byte(r, k0));
}
__device__ __forceinline__ void store_pair(ushort* base, int r, int k, unsigned w){
    *(unsigned*)((char*)base + lds_byte(r, k)) = w;
}
// write values (v0,v1) at (r, c0), (r, c0+1) into hi-plane and lo-plane
__device__ __forceinline__ void wpairs(ushort* Ahi, ushort* Alo, int r, int c0,
                                       float v0, float v1){
    unsigned hw = __builtin_amdgcn_perm(asu(v1), asu(v0), 0x07060302u);
    float l0 = v0 - asf(asu(v0) & 0xFFFF0000u);
    float l1 = v1 - asf(asu(v1) & 0xFFFF0000u);
    unsigned lw = bfu(l0) | (bfu(l1) << 16);
    store_pair(Ahi, r, c0, hw);
    store_pair(Alo, r, c0, lw);
}

// split 8 fp32 into hi/lo bf16x8 fragments (w_prep only)
__device__ __forceinline__ void split8(const float* f, short8& hi, short8& lo){
    unsigned hw[4], lw[4];
#pragma unroll
    for (int w = 0; w < 4; ++w){
        float a = f[2 * w], b = f[2 * w + 1];
        unsigned ha = asu(a) & 0xFFFF0000u, hb = asu(b) & 0xFFFF0000u;
        float la = a - asf(ha), lb = b - asf(hb);
        hw[w] = (ha >> 16) | hb;
        lw[w] = bfu(la) | (bfu(lb) << 16);
    }
    uint4 h4{hw[0], hw[1], hw[2], hw[3]}, l4{lw[0], lw[1], lw[2], lw[3]};
    hi = __builtin_bit_cast(short8, h4);
    lo = __builtin_bit_cast(short8, l4);
}

__device__ __forceinline__ f32x4 mfma_(short8 a, short8 b, f32x4 c){
    return __builtin_amdgcn_mfma_f32_16x16x32_bf16(a, b, c, 0, 0, 0);
}

__device__ __forceinline__ size_t wfrag_off(int l, int d, int ks, int ct, int L){
    return ((((size_t)(l * 3 + d) * 2 + ks) * 4 + ct) * 64 + (size_t)L) * 8;
}

__global__ void lad_init_kernel(float* __restrict__ lad, int n){
    int i = blockIdx.x * blockDim.x + threadIdx.x;
    if (i < n) lad[i] = 0.0f;
}

// Pre-split all weights into hi/lo bf16 MFMA fragments, once per launch.
__global__ __launch_bounds__(64)
void w_prep_kernel(const float* __restrict__ W0, const float* __restrict__ W1,
                   const float* __restrict__ W2, const float* __restrict__ W3,
                   unsigned* __restrict__ ws)
{
    const int b = blockIdx.x;
    const int L = threadIdx.x;
    if (b < 192){                        // W0/W1/W2 fragments
        const int l = b / 3, d = b - 3 * l;
        const float* Wd = (d == 0) ? W0 + (size_t)l * 64 * IN_DIM
                        : (d == 1) ? W1 + (size_t)l * 4096
                                   : W2 + (size_t)l * 4096;
        const int K  = (d == 0) ? IN_DIM : 64;
        const int c  = (L & 15);
        const int kb = (L >> 4) * 8;
#pragma unroll
        for (int ks = 0; ks < 2; ++ks)
#pragma unroll
            for (int ct = 0; ct < 4; ++ct){
                const float* wr = Wd + (size_t)(ct * 16 + c) * K + ks * 32 + kb;
                float wf[8];
#pragma unroll
                for (int j = 0; j < 8; ++j) wf[j] = wr[j];
                short8 wh, wl;
                split8(wf, wh, wl);
                size_t off = wfrag_off(l, d, ks, ct, L);
                *(short8*)(ws + off)     = wh;
                *(short8*)(ws + off + 4) = wl;
            }
    } else {                             // W3 fragments + w65 table
        const int l = b - 192;
        const int c  = (L & 15);
        const int kb = (L >> 4) * 8;
#pragma unroll
        for (int ks = 0; ks < 2; ++ks){
            float wf[8];
#pragma unroll
            for (int j = 0; j < 8; ++j)
                wf[j] = (c == 0) ? W3[l * 64 + ks * 32 + kb + j] : 0.0f;
            short8 wh, wl;
            split8(wf, wh, wl);
            size_t off = W3OFF + (((size_t)l * 2 + ks) * 64 + L) * 8;
            *(short8*)(ws + off)     = wh;
            *(short8*)(ws + off + 4) = wl;
        }
        ((float*)ws)[W65OFF + l * 64 + L] = W0[(size_t)l * 64 * IN_DIM + L * IN_DIM + 64];
    }
}

__global__ __launch_bounds__(256, 4)
void flow_mfma_kernel(const float* __restrict__ x,
                      const float* __restrict__ b0, const float* __restrict__ b1,
                      const float* __restrict__ b2, const float* __restrict__ b3,
                      const unsigned* __restrict__ wsp,
                      float* __restrict__ out_res, float* __restrict__ out_lad)
{
    __shared__ __attribute__((aligned(16))) ushort h_hi[4096], h_lo[4096];
    __shared__ __attribute__((aligned(16))) ushort t_hi[4096], t_lo[4096];

    const int l    = blockIdx.y;
    const int row0 = blockIdx.x * MB;
    const int tid  = threadIdx.x;
    const int L    = tid & 63;
    const int wr0  = (tid >> 6) * 16;   // this wave's private 16 rows
    const int rl   = L & 15;
    const int u    = L >> 4;
    const int r    = wr0 + rl;          // LDS row this lane owns

    // ---- stage x row-slice (each lane: row r, 16 k's); x65 stays in-register ----
    const float* xg = x + ((size_t)(row0 + r) * LATENTS + l) * IN_DIM;
    const float x65r = xg[64];
    {
        const int kb = u * 16;
        float v[16];
#pragma unroll
        for (int j = 0; j < 16; ++j) v[j] = xg[kb + j];
#pragma unroll
        for (int p = 0; p < 8; ++p)
            wpairs(h_hi, h_lo, r, kb + 2 * p, v[2 * p], v[2 * p + 1]);
    }

    f32x4 hacc[4], tacc[4];
    const int k0b = u * 8;

    auto loadw = [&](int d, int ks, int ct, short8& wh, short8& wl){
        size_t off = wfrag_off(l, d, ks, ct, L);
        wh = *(const short8*)(wsp + off);
        wl = *(const short8*)(wsp + off + 4);
    };

    // ---- layer 0: z = W0[:, :64]·x^T + b0, + rank-1 col-64; t1 = mask*w65 ----
    {
#pragma unroll
        for (int ct = 0; ct < 4; ++ct){
            float4 bv = *(const float4*)(b0 + l * 64 + ct * 16 + u * 4);
            hacc[ct] = (f32x4){bv.x, bv.y, bv.z, bv.w};
        }
#pragma unroll
        for (int ks = 0; ks < 2; ++ks){
            short8 ah = frag16(h_hi, r, ks * 32 + k0b);
            short8 al = frag16(h_lo, r, ks * 32 + k0b);
            __builtin_amdgcn_s_setprio(1);
#pragma unroll
            for (int ct = 0; ct < 4; ++ct){
                short8 wh, wl;
                loadw(0, ks, ct, wh, wl);
                hacc[ct] = mfma_(wh, ah, hacc[ct]);
                hacc[ct] = mfma_(wh, al, hacc[ct]);
                hacc[ct] = mfma_(wl, ah, hacc[ct]);
            }
            __builtin_amdgcn_s_setprio(0);
        }
        const float* w65p = (const float*)wsp + W65OFF + l * 64;
#pragma unroll
        for (int ct = 0; ct < 4; ++ct){
            float4 wv = *(const float4*)(w65p + ct * 16 + u * 4);
            float hv[4], tv[4];
            const float w65a[4] = {wv.x, wv.y, wv.z, wv.w};
#pragma unroll
            for (int i = 0; i < 4; ++i){
                float z = fmaf(x65r, w65a[i], hacc[ct][i]);
                hv[i] = fmaxf(z, SLOPE * z);
                tv[i] = (z >= 0.0f) ? w65a[i] : SLOPE * w65a[i];
            }
            const int c0 = ct * 16 + u * 4;
            wpairs(h_hi, h_lo, r, c0,     hv[0], hv[1]);
            wpairs(h_hi, h_lo, r, c0 + 2, hv[2], hv[3]);
            wpairs(t_hi, t_lo, r, c0,     tv[0], tv[1]);
            wpairs(t_hi, t_lo, r, c0 + 2, tv[2], tv[3]);
        }
    }

    // ---- layers 1,2: h,t GEMMs (A=weights, B=activations; D[c][r]) ----
    auto dense = [&](int d, const float* __restrict__ bl){
#pragma unroll
        for (int ct = 0; ct < 4; ++ct){
            float4 bv = *(const float4*)(bl + ct * 16 + u * 4);
            hacc[ct] = (f32x4){bv.x, bv.y, bv.z, bv.w};
            tacc[ct] = (f32x4){0.f, 0.f, 0.f, 0.f};
        }
#pragma unroll
        for (int ks = 0; ks < 2; ++ks){
            short8 ah = frag16(h_hi, r, ks * 32 + k0b);
            short8 al = frag16(h_lo, r, ks * 32 + k0b);
            short8 th = frag16(t_hi, r, ks * 32 + k0b);
            short8 tl = frag16(t_lo, r, ks * 32 + k0b);
            __builtin_amdgcn_s_setprio(1);
#pragma unroll
            for (int ct = 0; ct < 4; ++ct){
                short8 wh, wl;
                loadw(d, ks, ct, wh, wl);
                hacc[ct] = mfma_(wh, ah, hacc[ct]);
                hacc[ct] = mfma_(wh, al, hacc[ct]);
                hacc[ct] = mfma_(wl, ah, hacc[ct]);
                tacc[ct] = mfma_(wh, th, tacc[ct]);
                tacc[ct] = mfma_(wh, tl, tacc[ct]);
                tacc[ct] = mfma_(wl, th, tacc[ct]);
            }
            __builtin_amdgcn_s_setprio(0);
        }
#pragma unroll
        for (int ct = 0; ct < 4; ++ct){
            float hv[4], tv[4];
#pragma unroll
            for (int i = 0; i < 4; ++i){
                float z  = hacc[ct][i];
                float zt = tacc[ct][i];
                hv[i] = fmaxf(z, SLOPE * z);
                tv[i] = (z >= 0.0f) ? zt : SLOPE * zt;
            }
            const int c0 = ct * 16 + u * 4;
            wpairs(h_hi, h_lo, r, c0,     hv[0], hv[1]);
            wpairs(h_hi, h_lo, r, c0 + 2, hv[2], hv[3]);
            wpairs(t_hi, t_lo, r, c0,     tv[0], tv[1]);
            wpairs(t_hi, t_lo, r, c0 + 2, tv[2], tv[3]);
        }
    };
    dense(1, b1 + l * 64);
    dense(2, b2 + l * 64);

    // ---- layer 3: scalar head via MFMA (w3 in fragment col 0) ----
    {
        f32x4 so_a = (f32x4){0.f, 0.f, 0.f, 0.f};
        f32x4 sd_a = (f32x4){0.f, 0.f, 0.f, 0.f};
#pragma unroll
        for (int ks = 0; ks < 2; ++ks){
            short8 ah = frag16(h_hi, r, ks * 32 + k0b);
            short8 al = frag16(h_lo, r, ks * 32 + k0b);
            short8 th = frag16(t_hi, r, ks * 32 + k0b);
            short8 tl = frag16(t_lo, r, ks * 32 + k0b);
            size_t off = W3OFF + (((size_t)l * 2 + ks) * 64 + L) * 8;
            short8 wh = *(const short8*)(wsp + off);
            short8 wl = *(const short8*)(wsp + off + 4);
            __builtin_amdgcn_s_setprio(1);
            so_a = mfma_(wh, ah, so_a);
            so_a = mfma_(wh, al, so_a);
            so_a = mfma_(wl, ah, so_a);
            sd_a = mfma_(wh, th, sd_a);
            sd_a = mfma_(wh, tl, sd_a);
            sd_a = mfma_(wl, th, sd_a);
            __builtin_amdgcn_s_setprio(0);
        }
        if (L < 16){   // D row 0 lives in lanes 0-15, reg 0; col = batch row
            const int row = row0 + wr0 + L;
            out_res[(size_t)row * LATENTS + l] = so_a[0] + b3[l];
            atomicAdd(&out_lad[row], __logf(fabsf(sd_a[0]) + FEPS));
        }
    }
}

extern "C" void kernel_launch(void* const* d_in, const int* in_sizes, int n_in,
                              void* d_out, int out_size, void* d_ws, size_t ws_size,
                              hipStream_t stream)
{
    const float* x  = (const float*)d_in[0];
    const float* W0 = (const float*)d_in[1];
    const float* b0 = (const float*)d_in[2];
    const float* W1 = (const float*)d_in[3];
    const float* b1 = (const float*)d_in[4];
    const float* W2 = (const float*)d_in[5];
    const float* b2 = (const float*)d_in[6];
    const float* W3 = (const float*)d_in[7];
    const float* b3 = (const float*)d_in[8];

    const int B = in_sizes[0] / (LATENTS * IN_DIM);  // 8192
    float* out_res = (float*)d_out;
    float* out_lad = out_res + (size_t)B * LATENTS;
    unsigned* wsp  = (unsigned*)d_ws;   // ~3.4 MB of pre-split fragments

    lad_init_kernel<<<dim3((B + 255) / 256), dim3(256), 0, stream>>>(out_lad, B);
    w_prep_kernel<<<dim3(256), dim3(64), 0, stream>>>(W0, W1, W2, W3, wsp);
    flow_mfma_kernel<<<dim3(B / MB, LATENTS), dim3(256), 0, stream>>>(
        x, b0, b1, b2, b3, wsp, out_res, out_lad);
}

// Round 5
// 113.891 us; speedup vs baseline: 1.0050x; 1.0050x over previous
//
#include <hip/hip_runtime.h>
#include <hip/hip_bf16.h>
#include <cmath>

#define LATENTS 64
#define HID 64
#define IN_DIM 65
#define SLOPE 0.2f
#define FEPS 1e-8f
#define MB 64   // batch rows per block (16 per wave, 4 waves)

// ws layout (u32 units):
//  [0, 786432)      W0/W1/W2 frags: ((l*3+d)*2+ks)*4+ct, per-lane 8 u32 (hi4|lo4)
//  [W3OFF, +65536)  W3 frags: ((l*2+ks)*64+L)*8  (col0 = w3 at permuted slots)
//  [W65OFF, +4096)  w65[l][c] fp32 (W0 column 64)
#define W3OFF  786432u
#define W65OFF 851968u

// channel a -> B-slot s:  a = act*16 + au*4 + ai  ->  s = (act&1)*32 + au*8 + (act>>1)*4 + ai
// inverse (slot -> channel), used by w_prep:
#define A_OF_SLOT(s) ((((((s) >> 2) & 1) * 2 + ((s) >> 5)) * 16) + ((((s) >> 3) & 3) * 4) + ((s) & 3))

typedef __attribute__((ext_vector_type(8))) short short8;
typedef __attribute__((ext_vector_type(4))) float f32x4;

__device__ __forceinline__ unsigned asu(float f){ return __builtin_bit_cast(unsigned, f); }
__device__ __forceinline__ float    asf(unsigned u){ return __builtin_bit_cast(float, u); }
__device__ __forceinline__ unsigned bfu(float f){
    return (unsigned)__builtin_bit_cast(unsigned short, __float2bfloat16(f));
}

// split 8 fp32 into hi/lo bf16x8 fragments (hi = truncate, lo = RTNE remainder)
__device__ __forceinline__ void split8v(const float* f, short8& hi, short8& lo){
    unsigned hw[4], lw[4];
#pragma unroll
    for (int w = 0; w < 4; ++w){
        float a = f[2 * w], b = f[2 * w + 1];
        unsigned ha = asu(a) & 0xFFFF0000u, hb = asu(b) & 0xFFFF0000u;
        float la = a - asf(ha), lb = b - asf(hb);
        hw[w] = (ha >> 16) | hb;
        lw[w] = bfu(la) | (bfu(lb) << 16);
    }
    uint4 h4{hw[0], hw[1], hw[2], hw[3]}, l4{lw[0], lw[1], lw[2], lw[3]};
    hi = __builtin_bit_cast(short8, h4);
    lo = __builtin_bit_cast(short8, l4);
}

__device__ __forceinline__ f32x4 mfma_(short8 a, short8 b, f32x4 c){
    return __builtin_amdgcn_mfma_f32_16x16x32_bf16(a, b, c, 0, 0, 0);
}

__device__ __forceinline__ size_t wfrag_off(int l, int d, int ks, int ct, int L){
    return ((((size_t)(l * 3 + d) * 2 + ks) * 4 + ct) * 64 + (size_t)L) * 8;
}

__global__ void lad_init_kernel(float* __restrict__ lad, int n){
    int i = blockIdx.x * blockDim.x + threadIdx.x;
    if (i < n) lad[i] = 0.0f;
}

// Pre-split all weights into hi/lo bf16 MFMA fragments (k-slots permuted so that
// D-ownership == next-layer B-fragment), once per launch.
__global__ __launch_bounds__(64)
void w_prep_kernel(const float* __restrict__ W0, const float* __restrict__ W1,
                   const float* __restrict__ W2, const float* __restrict__ W3,
                   unsigned* __restrict__ ws)
{
    const int b = blockIdx.x;
    const int L = threadIdx.x;
    const int c  = L & 15;
    const int kb = (L >> 4) * 8;
    if (b < 192){                        // W0/W1/W2 fragments
        const int l = b / 3, d = b - 3 * l;
        const float* Wd = (d == 0) ? W0 + (size_t)l * 64 * IN_DIM
                        : (d == 1) ? W1 + (size_t)l * 4096
                                   : W2 + (size_t)l * 4096;
        const int K = (d == 0) ? IN_DIM : 64;
#pragma unroll
        for (int ks = 0; ks < 2; ++ks)
#pragma unroll
            for (int ct = 0; ct < 4; ++ct){
                float wf[8];
#pragma unroll
                for (int j = 0; j < 8; ++j){
                    const int s = ks * 32 + kb + j;
                    const int a = (d == 0) ? s : A_OF_SLOT(s);
                    wf[j] = Wd[(size_t)(ct * 16 + c) * K + a];
                }
                short8 wh, wl;
                split8v(wf, wh, wl);
                size_t off = wfrag_off(l, d, ks, ct, L);
                *(short8*)(ws + off)     = wh;
                *(short8*)(ws + off + 4) = wl;
            }
    } else {                             // W3 fragments + w65 table
        const int l = b - 192;
#pragma unroll
        for (int ks = 0; ks < 2; ++ks){
            float wf[8];
#pragma unroll
            for (int j = 0; j < 8; ++j)
                wf[j] = (c == 0) ? W3[l * 64 + A_OF_SLOT(ks * 32 + kb + j)] : 0.0f;
            short8 wh, wl;
            split8v(wf, wh, wl);
            size_t off = W3OFF + (((size_t)l * 2 + ks) * 64 + L) * 8;
            *(short8*)(ws + off)     = wh;
            *(short8*)(ws + off + 4) = wl;
        }
        ((float*)ws)[W65OFF + l * 64 + L] = W0[(size_t)l * 64 * IN_DIM + L * IN_DIM + 64];
    }
}

__global__ __launch_bounds__(256, 4)
void flow_mfma_kernel(const float* __restrict__ x,
                      const float* __restrict__ b0, const float* __restrict__ b1,
                      const float* __restrict__ b2, const float* __restrict__ b3,
                      const unsigned* __restrict__ wsp,
                      float* __restrict__ out_res, float* __restrict__ out_lad)
{
    const int l    = blockIdx.y;
    const int tid  = threadIdx.x;
    const int L    = tid & 63;
    const int u    = L >> 4;
    const int rl   = L & 15;
    const int grow = blockIdx.x * MB + (tid >> 6) * 16 + rl;   // this lane's batch row

    const float* xg = x + ((size_t)grow * LATENTS + l) * IN_DIM;

    // ---- per-lane x load at its own B-slots (k = ks*32 + 8u + j) ----
    float xv0[8], xv1[8];
#pragma unroll
    for (int j = 0; j < 8; ++j){
        xv0[j] = xg[8 * u + j];
        xv1[j] = xg[32 + 8 * u + j];
    }
    const float x65r = xg[64];

    short8 bh[2], bl2[2], th2[2], tl2[2];   // activation / tangent B-frags (hi/lo)
    split8v(xv0, bh[0], bl2[0]);
    split8v(xv1, bh[1], bl2[1]);

    f32x4 hacc[4], tacc[4];

    auto loadw = [&](int d, int ks, int ct, short8& wh, short8& wl){
        size_t off = wfrag_off(l, d, ks, ct, L);
        wh = *(const short8*)(wsp + off);
        wl = *(const short8*)(wsp + off + 4);
    };
    // frag[ks].elem[j] = v[(j>>2)*2+ks][j&3]  (channel->slot permutation, in-register)
    auto repack = [&](const float v[4][4], short8* hi, short8* lo){
#pragma unroll
        for (int ks = 0; ks < 2; ++ks){
            float f8[8] = {v[ks][0], v[ks][1], v[ks][2], v[ks][3],
                           v[2 + ks][0], v[2 + ks][1], v[2 + ks][2], v[2 + ks][3]};
            split8v(f8, hi[ks], lo[ks]);
        }
    };

    // ---- layer 0: z = W0[:, :64]·x^T + b0, + rank-1 col-64; t1 = mask*w65 ----
    {
#pragma unroll
        for (int ct = 0; ct < 4; ++ct){
            float4 bv = *(const float4*)(b0 + l * 64 + ct * 16 + u * 4);
            hacc[ct] = (f32x4){bv.x, bv.y, bv.z, bv.w};
        }
#pragma unroll
        for (int ks = 0; ks < 2; ++ks){
            __builtin_amdgcn_s_setprio(1);
#pragma unroll
            for (int ct = 0; ct < 4; ++ct){
                short8 wh, wl;
                loadw(0, ks, ct, wh, wl);
                hacc[ct] = mfma_(wh, bh[ks],  hacc[ct]);
                hacc[ct] = mfma_(wh, bl2[ks], hacc[ct]);
                hacc[ct] = mfma_(wl, bh[ks],  hacc[ct]);
            }
            __builtin_amdgcn_s_setprio(0);
        }
        const float* w65p = (const float*)wsp + W65OFF + l * 64;
        float hv[4][4], tv[4][4];
#pragma unroll
        for (int ct = 0; ct < 4; ++ct){
            float4 wv = *(const float4*)(w65p + ct * 16 + u * 4);
            const float wa[4] = {wv.x, wv.y, wv.z, wv.w};
#pragma unroll
            for (int i = 0; i < 4; ++i){
                float z = fmaf(x65r, wa[i], hacc[ct][i]);
                hv[ct][i] = fmaxf(z, SLOPE * z);
                tv[ct][i] = (z >= 0.0f) ? wa[i] : SLOPE * wa[i];
            }
        }
        repack(hv, bh, bl2);
        repack(tv, th2, tl2);
    }

    // ---- layers 1,2: h,t GEMMs fully in registers ----
    auto dense = [&](int d, const float* __restrict__ bl){
#pragma unroll
        for (int ct = 0; ct < 4; ++ct){
            float4 bv = *(const float4*)(bl + ct * 16 + u * 4);
            hacc[ct] = (f32x4){bv.x, bv.y, bv.z, bv.w};
            tacc[ct] = (f32x4){0.f, 0.f, 0.f, 0.f};
        }
#pragma unroll
        for (int ks = 0; ks < 2; ++ks){
            __builtin_amdgcn_s_setprio(1);
#pragma unroll
            for (int ct = 0; ct < 4; ++ct){
                short8 wh, wl;
                loadw(d, ks, ct, wh, wl);
                hacc[ct] = mfma_(wh, bh[ks],  hacc[ct]);
                hacc[ct] = mfma_(wh, bl2[ks], hacc[ct]);
                hacc[ct] = mfma_(wl, bh[ks],  hacc[ct]);
                tacc[ct] = mfma_(wh, th2[ks], tacc[ct]);
                tacc[ct] = mfma_(wh, tl2[ks], tacc[ct]);
                tacc[ct] = mfma_(wl, th2[ks], tacc[ct]);
            }
            __builtin_amdgcn_s_setprio(0);
        }
        float hv[4][4], tv[4][4];
#pragma unroll
        for (int ct = 0; ct < 4; ++ct)
#pragma unroll
            for (int i = 0; i < 4; ++i){
                float z  = hacc[ct][i];
                float zt = tacc[ct][i];
                hv[ct][i] = fmaxf(z, SLOPE * z);
                tv[ct][i] = (z >= 0.0f) ? zt : SLOPE * zt;
            }
        repack(hv, bh, bl2);
        repack(tv, th2, tl2);
    };
    dense(1, b1 + l * 64);
    dense(2, b2 + l * 64);

    // ---- layer 3: scalar head via MFMA (w3 in fragment col 0, permuted slots) ----
    {
        f32x4 so_a = (f32x4){0.f, 0.f, 0.f, 0.f};
        f32x4 sd_a = (f32x4){0.f, 0.f, 0.f, 0.f};
#pragma unroll
        for (int ks = 0; ks < 2; ++ks){
            size_t off = W3OFF + (((size_t)l * 2 + ks) * 64 + L) * 8;
            short8 wh = *(const short8*)(wsp + off);
            short8 wl = *(const short8*)(wsp + off + 4);
            __builtin_amdgcn_s_setprio(1);
            so_a = mfma_(wh, bh[ks],  so_a);
            so_a = mfma_(wh, bl2[ks], so_a);
            so_a = mfma_(wl, bh[ks],  so_a);
            sd_a = mfma_(wh, th2[ks], sd_a);
            sd_a = mfma_(wh, tl2[ks], sd_a);
            sd_a = mfma_(wl, th2[ks], sd_a);
            __builtin_amdgcn_s_setprio(0);
        }
        if (u == 0){   // D row 0 (lanes 0-15, reg 0); col = batch row
            out_res[(size_t)grow * LATENTS + l] = so_a[0] + b3[l];
            atomicAdd(&out_lad[grow], __logf(fabsf(sd_a[0]) + FEPS));
        }
    }
}

extern "C" void kernel_launch(void* const* d_in, const int* in_sizes, int n_in,
                              void* d_out, int out_size, void* d_ws, size_t ws_size,
                              hipStream_t stream)
{
    const float* x  = (const float*)d_in[0];
    const float* W0 = (const float*)d_in[1];
    const float* b0 = (const float*)d_in[2];
    const float* W1 = (const float*)d_in[3];
    const float* b1 = (const float*)d_in[4];
    const float* W2 = (const float*)d_in[5];
    const float* b2 = (const float*)d_in[6];
    const float* W3 = (const float*)d_in[7];
    const float* b3 = (const float*)d_in[8];

    const int B = in_sizes[0] / (LATENTS * IN_DIM);  // 8192
    float* out_res = (float*)d_out;
    float* out_lad = out_res + (size_t)B * LATENTS;
    unsigned* wsp  = (unsigned*)d_ws;   // ~3.4 MB of pre-split fragments

    lad_init_kernel<<<dim3((B + 255) / 256), dim3(256), 0, stream>>>(out_lad, B);
    w_prep_kernel<<<dim3(256), dim3(64), 0, stream>>>(W0, W1, W2, W3, wsp);
    flow_mfma_kernel<<<dim3(B / MB, LATENTS), dim3(256), 0, stream>>>(
        x, b0, b1, b2, b3, wsp, out_res, out_lad);
}

// Round 6
// 103.429 us; speedup vs baseline: 1.1067x; 1.1012x over previous
//
#include <hip/hip_runtime.h>
#include <hip/hip_bf16.h>
#include <cmath>

#define LATENTS 64
#define HID 64
#define IN_DIM 65
#define SLOPE 0.2f
#define FEPS 1e-8f
#define RPB 128   // rows per block: 4 waves x 2 tiles x 16 rows

// ws layout (u32 units):
//  [0, 786432)      W0/W1/W2 frags: ((l*3+d)*2+ks)*4+ct, per-lane 8 u32 (hi4|lo4)
//  [W3OFF, +65536)  W3 frags: ((l*2+ks)*64+L)*8  (col0 = w3 at permuted slots)
//  [W65OFF, +4096)  w65[l][c] fp32 (W0 column 64)
#define W3OFF  786432u
#define W65OFF 851968u

// channel a = act*16+au*4+ai  ->  slot s = (act&1)*32 + au*8 + (act>>1)*4 + ai
#define A_OF_SLOT(s) ((((((s) >> 2) & 1) * 2 + ((s) >> 5)) * 16) + ((((s) >> 3) & 3) * 4) + ((s) & 3))

typedef __attribute__((ext_vector_type(8))) short short8;
typedef __attribute__((ext_vector_type(4))) float f32x4;

__device__ __forceinline__ unsigned asu(float f){ return __builtin_bit_cast(unsigned, f); }
__device__ __forceinline__ float    asf(unsigned u){ return __builtin_bit_cast(float, u); }
__device__ __forceinline__ unsigned bfu(float f){
    return (unsigned)__builtin_bit_cast(unsigned short, __float2bfloat16(f));
}

// split 8 fp32 into hi/lo bf16x8 fragments (hi = truncate, lo = RTNE remainder)
__device__ __forceinline__ void split8v(const float* f, short8& hi, short8& lo){
    unsigned hw[4], lw[4];
#pragma unroll
    for (int w = 0; w < 4; ++w){
        float a = f[2 * w], b = f[2 * w + 1];
        unsigned ha = asu(a) & 0xFFFF0000u, hb = asu(b) & 0xFFFF0000u;
        float la = a - asf(ha), lb = b - asf(hb);
        hw[w] = (ha >> 16) | hb;
        lw[w] = bfu(la) | (bfu(lb) << 16);
    }
    uint4 h4{hw[0], hw[1], hw[2], hw[3]}, l4{lw[0], lw[1], lw[2], lw[3]};
    hi = __builtin_bit_cast(short8, h4);
    lo = __builtin_bit_cast(short8, l4);
}

__device__ __forceinline__ f32x4 mfma_(short8 a, short8 b, f32x4 c){
    return __builtin_amdgcn_mfma_f32_16x16x32_bf16(a, b, c, 0, 0, 0);
}

__device__ __forceinline__ size_t wfrag_off(int l, int d, int ks, int ct, int L){
    return ((((size_t)(l * 3 + d) * 2 + ks) * 4 + ct) * 64 + (size_t)L) * 8;
}

__device__ __forceinline__ void load_layer(const unsigned* __restrict__ wsp,
                                           int l, int d, int L,
                                           short8 (&wh)[2][4], short8 (&wl)[2][4]){
#pragma unroll
    for (int ks = 0; ks < 2; ++ks)
#pragma unroll
        for (int ct = 0; ct < 4; ++ct){
            size_t off = wfrag_off(l, d, ks, ct, L);
            wh[ks][ct] = *(const short8*)(wsp + off);
            wl[ks][ct] = *(const short8*)(wsp + off + 4);
        }
}

__global__ void lad_init_kernel(float* __restrict__ lad, int n){
    int i = blockIdx.x * blockDim.x + threadIdx.x;
    if (i < n) lad[i] = 0.0f;
}

// Pre-split all weights into hi/lo bf16 MFMA fragments (k-slots permuted so that
// D-ownership == next-layer B-fragment), once per launch.
__global__ __launch_bounds__(64)
void w_prep_kernel(const float* __restrict__ W0, const float* __restrict__ W1,
                   const float* __restrict__ W2, const float* __restrict__ W3,
                   unsigned* __restrict__ ws)
{
    const int b = blockIdx.x;
    const int L = threadIdx.x;
    const int c  = L & 15;
    const int kb = (L >> 4) * 8;
    if (b < 192){                        // W0/W1/W2 fragments
        const int l = b / 3, d = b - 3 * l;
        const float* Wd = (d == 0) ? W0 + (size_t)l * 64 * IN_DIM
                        : (d == 1) ? W1 + (size_t)l * 4096
                                   : W2 + (size_t)l * 4096;
        const int K = (d == 0) ? IN_DIM : 64;
#pragma unroll
        for (int ks = 0; ks < 2; ++ks)
#pragma unroll
            for (int ct = 0; ct < 4; ++ct){
                float wf[8];
#pragma unroll
                for (int j = 0; j < 8; ++j){
                    const int s = ks * 32 + kb + j;
                    const int a = (d == 0) ? s : A_OF_SLOT(s);
                    wf[j] = Wd[(size_t)(ct * 16 + c) * K + a];
                }
                short8 wh, wl;
                split8v(wf, wh, wl);
                size_t off = wfrag_off(l, d, ks, ct, L);
                *(short8*)(ws + off)     = wh;
                *(short8*)(ws + off + 4) = wl;
            }
    } else {                             // W3 fragments + w65 table
        const int l = b - 192;
#pragma unroll
        for (int ks = 0; ks < 2; ++ks){
            float wf[8];
#pragma unroll
            for (int j = 0; j < 8; ++j)
                wf[j] = (c == 0) ? W3[l * 64 + A_OF_SLOT(ks * 32 + kb + j)] : 0.0f;
            short8 wh, wl;
            split8v(wf, wh, wl);
            size_t off = W3OFF + (((size_t)l * 2 + ks) * 64 + L) * 8;
            *(short8*)(ws + off)     = wh;
            *(short8*)(ws + off + 4) = wl;
        }
        ((float*)ws)[W65OFF + l * 64 + L] = W0[(size_t)l * 64 * IN_DIM + L * IN_DIM + 64];
    }
}

__global__ __launch_bounds__(256, 2)
void flow_mfma_kernel(const float* __restrict__ x,
                      const float* __restrict__ b0, const float* __restrict__ b1,
                      const float* __restrict__ b2, const float* __restrict__ b3,
                      const unsigned* __restrict__ wsp,
                      float* __restrict__ out_res, float* __restrict__ out_lad)
{
    const int l   = blockIdx.y;
    const int tid = threadIdx.x;
    const int L   = tid & 63;
    const int u   = L >> 4;
    const int g0  = blockIdx.x * RPB + (tid >> 6) * 32 + (L & 15);  // tile-0 row
    const int g1  = g0 + 16;                                         // tile-1 row

    const float* xg0 = x + ((size_t)g0 * LATENTS + l) * IN_DIM;
    const float* xg1 = x + ((size_t)g1 * LATENTS + l) * IN_DIM;

    // ---- issue x loads (both tiles) ----
    float xv[2][16];
    float x65r[2];
#pragma unroll
    for (int j = 0; j < 8; ++j){
        xv[0][j]     = xg0[8 * u + j];
        xv[0][8 + j] = xg0[32 + 8 * u + j];
        xv[1][j]     = xg1[8 * u + j];
        xv[1][8 + j] = xg1[32 + 8 * u + j];
    }
    x65r[0] = xg0[64];
    x65r[1] = xg1[64];

    // ---- issue layer-0 weights + w65 + b0 ----
    short8 w0h[2][4], w0l[2][4];
    load_layer(wsp, l, 0, L, w0h, w0l);
    const float* w65p = (const float*)wsp + W65OFF + l * 64;
    float4 w65v[4], bv0[4];
#pragma unroll
    for (int ct = 0; ct < 4; ++ct){
        w65v[ct] = *(const float4*)(w65p + ct * 16 + u * 4);
        bv0[ct]  = *(const float4*)(b0 + l * 64 + ct * 16 + u * 4);
    }

    // ---- split x into B-frags ----
    short8 bh[2][2], bl2[2][2], th2[2][2], tl2[2][2];
#pragma unroll
    for (int t = 0; t < 2; ++t){
        split8v(&xv[t][0], bh[t][0], bl2[t][0]);
        split8v(&xv[t][8], bh[t][1], bl2[t][1]);
    }

    // ---- prefetch layer-1 weights + b1 ----
    short8 w1h[2][4], w1l[2][4];
    load_layer(wsp, l, 1, L, w1h, w1l);
    float4 bv1[4];
#pragma unroll
    for (int ct = 0; ct < 4; ++ct)
        bv1[ct] = *(const float4*)(b1 + l * 64 + ct * 16 + u * 4);

    f32x4 ha[2][4], ta[2][4];

    // helper: epilogue repack (channel->slot permutation, in-register)
    auto repack = [&](int t, const float v[4][4], short8 (&hi)[2][2], short8 (&lo)[2][2]){
#pragma unroll
        for (int ks = 0; ks < 2; ++ks){
            float f8[8] = {v[ks][0], v[ks][1], v[ks][2], v[ks][3],
                           v[2 + ks][0], v[2 + ks][1], v[2 + ks][2], v[2 + ks][3]};
            split8v(f8, hi[t][ks], lo[t][ks]);
        }
    };

    // ---- layer 0 compute (h only) ----
    {
#pragma unroll
        for (int t = 0; t < 2; ++t)
#pragma unroll
            for (int ct = 0; ct < 4; ++ct)
                ha[t][ct] = (f32x4){bv0[ct].x, bv0[ct].y, bv0[ct].z, bv0[ct].w};
#pragma unroll
        for (int ks = 0; ks < 2; ++ks){
            __builtin_amdgcn_s_setprio(1);
#pragma unroll
            for (int ct = 0; ct < 4; ++ct)
#pragma unroll
                for (int t = 0; t < 2; ++t){
                    ha[t][ct] = mfma_(w0h[ks][ct], bh[t][ks],  ha[t][ct]);
                    ha[t][ct] = mfma_(w0h[ks][ct], bl2[t][ks], ha[t][ct]);
                    ha[t][ct] = mfma_(w0l[ks][ct], bh[t][ks],  ha[t][ct]);
                }
            __builtin_amdgcn_s_setprio(0);
        }
        // rank-1 col-64 update + activation; tangent = mask * w65
#pragma unroll
        for (int t = 0; t < 2; ++t){
            float hv[4][4], tv[4][4];
#pragma unroll
            for (int ct = 0; ct < 4; ++ct){
                const float wa[4] = {w65v[ct].x, w65v[ct].y, w65v[ct].z, w65v[ct].w};
#pragma unroll
                for (int i = 0; i < 4; ++i){
                    float z = fmaf(x65r[t], wa[i], ha[t][ct][i]);
                    hv[ct][i] = fmaxf(z, SLOPE * z);
                    tv[ct][i] = (z >= 0.0f) ? wa[i] : SLOPE * wa[i];
                }
            }
            repack(t, hv, bh, bl2);
            repack(t, tv, th2, tl2);
        }
    }

    // ---- prefetch layer-2 weights + b2 ----
    short8 w2h[2][4], w2l[2][4];
    load_layer(wsp, l, 2, L, w2h, w2l);
    float4 bv2[4];
#pragma unroll
    for (int ct = 0; ct < 4; ++ct)
        bv2[ct] = *(const float4*)(b2 + l * 64 + ct * 16 + u * 4);

    // generic dense layer (h + t), both tiles
    auto dense2 = [&](const short8 (&wh)[2][4], const short8 (&wl)[2][4],
                      const float4 (&bv)[4]){
#pragma unroll
        for (int t = 0; t < 2; ++t)
#pragma unroll
            for (int ct = 0; ct < 4; ++ct){
                ha[t][ct] = (f32x4){bv[ct].x, bv[ct].y, bv[ct].z, bv[ct].w};
                ta[t][ct] = (f32x4){0.f, 0.f, 0.f, 0.f};
            }
#pragma unroll
        for (int ks = 0; ks < 2; ++ks){
            __builtin_amdgcn_s_setprio(1);
#pragma unroll
            for (int ct = 0; ct < 4; ++ct)
#pragma unroll
                for (int t = 0; t < 2; ++t){
                    ha[t][ct] = mfma_(wh[ks][ct], bh[t][ks],  ha[t][ct]);
                    ha[t][ct] = mfma_(wh[ks][ct], bl2[t][ks], ha[t][ct]);
                    ha[t][ct] = mfma_(wl[ks][ct], bh[t][ks],  ha[t][ct]);
                    ta[t][ct] = mfma_(wh[ks][ct], th2[t][ks], ta[t][ct]);
                    ta[t][ct] = mfma_(wh[ks][ct], tl2[t][ks], ta[t][ct]);
                    ta[t][ct] = mfma_(wl[ks][ct], th2[t][ks], ta[t][ct]);
                }
            __builtin_amdgcn_s_setprio(0);
        }
#pragma unroll
        for (int t = 0; t < 2; ++t){
            float hv[4][4], tv[4][4];
#pragma unroll
            for (int ct = 0; ct < 4; ++ct)
#pragma unroll
                for (int i = 0; i < 4; ++i){
                    float z  = ha[t][ct][i];
                    float zt = ta[t][ct][i];
                    hv[ct][i] = fmaxf(z, SLOPE * z);
                    tv[ct][i] = (z >= 0.0f) ? zt : SLOPE * zt;
                }
            repack(t, hv, bh, bl2);
            repack(t, tv, th2, tl2);
        }
    };

    // ---- layer 1 compute ----
    dense2(w1h, w1l, bv1);

    // ---- prefetch layer-3 (W3) fragments ----
    short8 w3h[2], w3l[2];
#pragma unroll
    for (int ks = 0; ks < 2; ++ks){
        size_t off = W3OFF + (((size_t)l * 2 + ks) * 64 + L) * 8;
        w3h[ks] = *(const short8*)(wsp + off);
        w3l[ks] = *(const short8*)(wsp + off + 4);
    }

    // ---- layer 2 compute ----
    dense2(w2h, w2l, bv2);

    // ---- layer 3: scalar head via MFMA ----
    {
        f32x4 so[2], sd[2];
#pragma unroll
        for (int t = 0; t < 2; ++t){
            so[t] = (f32x4){0.f, 0.f, 0.f, 0.f};
            sd[t] = (f32x4){0.f, 0.f, 0.f, 0.f};
        }
#pragma unroll
        for (int ks = 0; ks < 2; ++ks){
            __builtin_amdgcn_s_setprio(1);
#pragma unroll
            for (int t = 0; t < 2; ++t){
                so[t] = mfma_(w3h[ks], bh[t][ks],  so[t]);
                so[t] = mfma_(w3h[ks], bl2[t][ks], so[t]);
                so[t] = mfma_(w3l[ks], bh[t][ks],  so[t]);
                sd[t] = mfma_(w3h[ks], th2[t][ks], sd[t]);
                sd[t] = mfma_(w3h[ks], tl2[t][ks], sd[t]);
                sd[t] = mfma_(w3l[ks], th2[t][ks], sd[t]);
            }
            __builtin_amdgcn_s_setprio(0);
        }
        if (u == 0){   // D row 0 (lanes 0-15, reg 0); col = batch row
            const float b3v = b3[l];
            out_res[(size_t)g0 * LATENTS + l] = so[0][0] + b3v;
            out_res[(size_t)g1 * LATENTS + l] = so[1][0] + b3v;
            atomicAdd(&out_lad[g0], __logf(fabsf(sd[0][0]) + FEPS));
            atomicAdd(&out_lad[g1], __logf(fabsf(sd[1][0]) + FEPS));
        }
    }
}

extern "C" void kernel_launch(void* const* d_in, const int* in_sizes, int n_in,
                              void* d_out, int out_size, void* d_ws, size_t ws_size,
                              hipStream_t stream)
{
    const float* x  = (const float*)d_in[0];
    const float* W0 = (const float*)d_in[1];
    const float* b0 = (const float*)d_in[2];
    const float* W1 = (const float*)d_in[3];
    const float* b1 = (const float*)d_in[4];
    const float* W2 = (const float*)d_in[5];
    const float* b2 = (const float*)d_in[6];
    const float* W3 = (const float*)d_in[7];
    const float* b3 = (const float*)d_in[8];

    const int B = in_sizes[0] / (LATENTS * IN_DIM);  // 8192
    float* out_res = (float*)d_out;
    float* out_lad = out_res + (size_t)B * LATENTS;
    unsigned* wsp  = (unsigned*)d_ws;   // ~3.4 MB of pre-split fragments

    lad_init_kernel<<<dim3((B + 255) / 256), dim3(256), 0, stream>>>(out_lad, B);
    w_prep_kernel<<<dim3(256), dim3(64), 0, stream>>>(W0, W1, W2, W3, wsp);
    flow_mfma_kernel<<<dim3(B / RPB, LATENTS), dim3(256), 0, stream>>>(
        x, b0, b1, b2, b3, wsp, out_res, out_lad);
}

// Round 7
// 87.509 us; speedup vs baseline: 1.3080x; 1.1819x over previous
//
#include <hip/hip_runtime.h>
#include <hip/hip_bf16.h>
#include <cmath>

#define LATENTS 64
#define HID 64
#define IN_DIM 65
#define SLOPE 0.2f
#define FEPS 1e-8f
#define RPB 128            // rows per block: 4 waves x 2 tiles x 16 rows
#define WBYTES 53248       // per-latent pre-split weights: 3*16KB (W0-2) + 4KB (W3)
#define W65_BYTE (64 * WBYTES)

// channel a = act*16+au*4+ai  ->  slot s = (act&1)*32 + au*8 + (act>>1)*4 + ai
#define A_OF_SLOT(s) ((((((s) >> 2) & 1) * 2 + ((s) >> 5)) * 16) + ((((s) >> 3) & 3) * 4) + ((s) & 3))

typedef __attribute__((ext_vector_type(8))) short short8;
typedef __attribute__((ext_vector_type(4))) float f32x4;
typedef __attribute__((address_space(1))) const unsigned GASU;
typedef __attribute__((address_space(3))) unsigned LASU;

__device__ __forceinline__ unsigned asu(float f){ return __builtin_bit_cast(unsigned, f); }
__device__ __forceinline__ float    asf(unsigned u){ return __builtin_bit_cast(float, u); }
__device__ __forceinline__ unsigned bfu(float f){
    return (unsigned)__builtin_bit_cast(unsigned short, __float2bfloat16(f));
}

// split 8 fp32 into hi/lo bf16x8 fragments (hi = truncate, lo = RTNE remainder)
__device__ __forceinline__ void split8v(const float* f, short8& hi, short8& lo){
    unsigned hw[4], lw[4];
#pragma unroll
    for (int w = 0; w < 4; ++w){
        float a = f[2 * w], b = f[2 * w + 1];
        unsigned ha = asu(a) & 0xFFFF0000u, hb = asu(b) & 0xFFFF0000u;
        float la = a - asf(ha), lb = b - asf(hb);
        hw[w] = (ha >> 16) | hb;
        lw[w] = bfu(la) | (bfu(lb) << 16);
    }
    uint4 h4{hw[0], hw[1], hw[2], hw[3]}, l4{lw[0], lw[1], lw[2], lw[3]};
    hi = __builtin_bit_cast(short8, h4);
    lo = __builtin_bit_cast(short8, l4);
}

__device__ __forceinline__ f32x4 mfma_(short8 a, short8 b, f32x4 c){
    return __builtin_amdgcn_mfma_f32_16x16x32_bf16(a, b, c, 0, 0, 0);
}

__global__ void lad_init_kernel(float* __restrict__ lad, int n){
    int i = blockIdx.x * blockDim.x + threadIdx.x;
    if (i < n) lad[i] = 0.0f;
}

// Pre-split all weights into hi/lo bf16 MFMA fragments, laid out per-latent as one
// contiguous 52KB block (hi-plane / lo-plane separated for 16B-stride ds_reads).
__global__ __launch_bounds__(64)
void w_prep_kernel(const float* __restrict__ W0, const float* __restrict__ W1,
                   const float* __restrict__ W2, const float* __restrict__ W3,
                   char* __restrict__ ws)
{
    const int b = blockIdx.x;
    const int L = threadIdx.x;
    const int c  = L & 15;
    const int kb = (L >> 4) * 8;
    if (b < 192){                        // W0/W1/W2 fragments
        const int l = b / 3, d = b - 3 * l;
        const float* Wd = (d == 0) ? W0 + (size_t)l * 64 * IN_DIM
                        : (d == 1) ? W1 + (size_t)l * 4096
                                   : W2 + (size_t)l * 4096;
        const int K = (d == 0) ? IN_DIM : 64;
#pragma unroll
        for (int ks = 0; ks < 2; ++ks)
#pragma unroll
            for (int ct = 0; ct < 4; ++ct){
                float wf[8];
#pragma unroll
                for (int j = 0; j < 8; ++j){
                    const int s = ks * 32 + kb + j;
                    const int a = (d == 0) ? s : A_OF_SLOT(s);
                    wf[j] = Wd[(size_t)(ct * 16 + c) * K + a];
                }
                short8 wh, wl;
                split8v(wf, wh, wl);
                char* base = ws + (size_t)l * WBYTES + d * 16384 + (ks * 4 + ct) * 1024 + L * 16;
                *(short8*)base            = wh;
                *(short8*)(base + 8192)   = wl;
            }
    } else {                             // W3 fragments + w65 table
        const int l = b - 192;
#pragma unroll
        for (int ks = 0; ks < 2; ++ks){
            float wf[8];
#pragma unroll
            for (int j = 0; j < 8; ++j)
                wf[j] = (c == 0) ? W3[l * 64 + A_OF_SLOT(ks * 32 + kb + j)] : 0.0f;
            short8 wh, wl;
            split8v(wf, wh, wl);
            char* base = ws + (size_t)l * WBYTES + 49152 + ks * 1024 + L * 16;
            *(short8*)base          = wh;
            *(short8*)(base + 2048) = wl;
        }
        ((float*)(ws + W65_BYTE))[l * 64 + L] =
            W0[(size_t)l * 64 * IN_DIM + L * IN_DIM + 64];
    }
}

__global__ __launch_bounds__(256, 2)
void flow_mfma_kernel(const float* __restrict__ x,
                      const float* __restrict__ b0, const float* __restrict__ b1,
                      const float* __restrict__ b2, const float* __restrict__ b3,
                      const char* __restrict__ ws,
                      float* __restrict__ out_res, float* __restrict__ out_lad)
{
    __shared__ __attribute__((aligned(16))) char wlds[WBYTES];

    const int l   = blockIdx.y;
    const int tid = threadIdx.x;
    const int L   = tid & 63;
    const int wv  = tid >> 6;
    const int u   = L >> 4;
    const int g0  = blockIdx.x * RPB + wv * 32 + (L & 15);  // tile-0 row
    const int g1  = g0 + 16;                                 // tile-1 row

    // ---- stage this latent's 52KB weight block into LDS (13 x 16B per thread) ----
    const char* gsrc = ws + (size_t)l * WBYTES;
#pragma unroll
    for (int i = 0; i < 13; ++i){
        const int off = (i * 256 + wv * 64) * 16;
        __builtin_amdgcn_global_load_lds((GASU*)(gsrc + off + L * 16),
                                         (LASU*)(wlds + off), 16, 0, 0);
    }

    // ---- x loads + biases + w65 (overlap staging latency) ----
    const float* xg0 = x + ((size_t)g0 * LATENTS + l) * IN_DIM;
    const float* xg1 = x + ((size_t)g1 * LATENTS + l) * IN_DIM;
    float xv[2][16];
    float x65r[2];
#pragma unroll
    for (int j = 0; j < 8; ++j){
        xv[0][j]     = xg0[8 * u + j];
        xv[0][8 + j] = xg0[32 + 8 * u + j];
        xv[1][j]     = xg1[8 * u + j];
        xv[1][8 + j] = xg1[32 + 8 * u + j];
    }
    x65r[0] = xg0[64];
    x65r[1] = xg1[64];

    const float* w65p = (const float*)(ws + W65_BYTE) + l * 64;
    float4 w65v[4], bv0[4], bv1[4], bv2[4];
#pragma unroll
    for (int ct = 0; ct < 4; ++ct){
        w65v[ct] = *(const float4*)(w65p + ct * 16 + u * 4);
        bv0[ct]  = *(const float4*)(b0 + l * 64 + ct * 16 + u * 4);
        bv1[ct]  = *(const float4*)(b1 + l * 64 + ct * 16 + u * 4);
        bv2[ct]  = *(const float4*)(b2 + l * 64 + ct * 16 + u * 4);
    }

    // ---- split x into B-frags ----
    short8 bh[2][2], bl2[2][2], th2[2][2], tl2[2][2];
#pragma unroll
    for (int t = 0; t < 2; ++t){
        split8v(&xv[t][0], bh[t][0], bl2[t][0]);
        split8v(&xv[t][8], bh[t][1], bl2[t][1]);
    }

    __syncthreads();   // weights resident in LDS

    f32x4 ha[2][4], ta[2][4];

    auto ldw = [&](int d, int ks, int ct, short8& wh, short8& wl){
        const char* p = wlds + d * 16384 + (ks * 4 + ct) * 1024 + (L << 4);
        wh = *(const short8*)p;
        wl = *(const short8*)(p + 8192);
    };
    auto repack = [&](int t, const float v[4][4], short8 (&hi)[2][2], short8 (&lo)[2][2]){
#pragma unroll
        for (int ks = 0; ks < 2; ++ks){
            float f8[8] = {v[ks][0], v[ks][1], v[ks][2], v[ks][3],
                           v[2 + ks][0], v[2 + ks][1], v[2 + ks][2], v[2 + ks][3]};
            split8v(f8, hi[t][ks], lo[t][ks]);
        }
    };

    // ---- layer 0 (h only) + rank-1 col-64; tangent = mask * w65 ----
    {
#pragma unroll
        for (int t = 0; t < 2; ++t)
#pragma unroll
            for (int ct = 0; ct < 4; ++ct)
                ha[t][ct] = (f32x4){bv0[ct].x, bv0[ct].y, bv0[ct].z, bv0[ct].w};
#pragma unroll
        for (int ks = 0; ks < 2; ++ks){
#pragma unroll
            for (int ct = 0; ct < 4; ++ct){
                short8 wh, wl;
                ldw(0, ks, ct, wh, wl);
                __builtin_amdgcn_s_setprio(1);
#pragma unroll
                for (int t = 0; t < 2; ++t){
                    ha[t][ct] = mfma_(wh, bh[t][ks],  ha[t][ct]);
                    ha[t][ct] = mfma_(wh, bl2[t][ks], ha[t][ct]);
                    ha[t][ct] = mfma_(wl, bh[t][ks],  ha[t][ct]);
                }
                __builtin_amdgcn_s_setprio(0);
            }
        }
#pragma unroll
        for (int t = 0; t < 2; ++t){
            float hv[4][4], tv[4][4];
#pragma unroll
            for (int ct = 0; ct < 4; ++ct){
                const float wa[4] = {w65v[ct].x, w65v[ct].y, w65v[ct].z, w65v[ct].w};
#pragma unroll
                for (int i = 0; i < 4; ++i){
                    float z = fmaf(x65r[t], wa[i], ha[t][ct][i]);
                    hv[ct][i] = fmaxf(z, SLOPE * z);
                    tv[ct][i] = (z >= 0.0f) ? wa[i] : SLOPE * wa[i];
                }
            }
            repack(t, hv, bh, bl2);
            repack(t, tv, th2, tl2);
        }
    }

    // ---- layers 1,2: h,t GEMMs, weights JIT from LDS ----
    auto dense2 = [&](int d, const float4 (&bv)[4]){
#pragma unroll
        for (int t = 0; t < 2; ++t)
#pragma unroll
            for (int ct = 0; ct < 4; ++ct){
                ha[t][ct] = (f32x4){bv[ct].x, bv[ct].y, bv[ct].z, bv[ct].w};
                ta[t][ct] = (f32x4){0.f, 0.f, 0.f, 0.f};
            }
#pragma unroll
        for (int ks = 0; ks < 2; ++ks){
#pragma unroll
            for (int ct = 0; ct < 4; ++ct){
                short8 wh, wl;
                ldw(d, ks, ct, wh, wl);
                __builtin_amdgcn_s_setprio(1);
#pragma unroll
                for (int t = 0; t < 2; ++t){
                    ha[t][ct] = mfma_(wh, bh[t][ks],  ha[t][ct]);
                    ha[t][ct] = mfma_(wh, bl2[t][ks], ha[t][ct]);
                    ha[t][ct] = mfma_(wl, bh[t][ks],  ha[t][ct]);
                    ta[t][ct] = mfma_(wh, th2[t][ks], ta[t][ct]);
                    ta[t][ct] = mfma_(wh, tl2[t][ks], ta[t][ct]);
                    ta[t][ct] = mfma_(wl, th2[t][ks], ta[t][ct]);
                }
                __builtin_amdgcn_s_setprio(0);
            }
        }
#pragma unroll
        for (int t = 0; t < 2; ++t){
            float hv[4][4], tv[4][4];
#pragma unroll
            for (int ct = 0; ct < 4; ++ct)
#pragma unroll
                for (int i = 0; i < 4; ++i){
                    float z  = ha[t][ct][i];
                    float zt = ta[t][ct][i];
                    hv[ct][i] = fmaxf(z, SLOPE * z);
                    tv[ct][i] = (z >= 0.0f) ? zt : SLOPE * zt;
                }
            repack(t, hv, bh, bl2);
            repack(t, tv, th2, tl2);
        }
    };
    dense2(1, bv1);
    dense2(2, bv2);

    // ---- layer 3: scalar head via MFMA (w3 in fragment col 0) ----
    {
        f32x4 so[2], sd[2];
#pragma unroll
        for (int t = 0; t < 2; ++t){
            so[t] = (f32x4){0.f, 0.f, 0.f, 0.f};
            sd[t] = (f32x4){0.f, 0.f, 0.f, 0.f};
        }
#pragma unroll
        for (int ks = 0; ks < 2; ++ks){
            const char* p = wlds + 49152 + ks * 1024 + (L << 4);
            short8 wh = *(const short8*)p;
            short8 wl = *(const short8*)(p + 2048);
            __builtin_amdgcn_s_setprio(1);
#pragma unroll
            for (int t = 0; t < 2; ++t){
                so[t] = mfma_(wh, bh[t][ks],  so[t]);
                so[t] = mfma_(wh, bl2[t][ks], so[t]);
                so[t] = mfma_(wl, bh[t][ks],  so[t]);
                sd[t] = mfma_(wh, th2[t][ks], sd[t]);
                sd[t] = mfma_(wh, tl2[t][ks], sd[t]);
                sd[t] = mfma_(wl, th2[t][ks], sd[t]);
            }
            __builtin_amdgcn_s_setprio(0);
        }
        if (u == 0){   // D row 0 (lanes 0-15, reg 0); col = batch row
            const float b3v = b3[l];
            out_res[(size_t)g0 * LATENTS + l] = so[0][0] + b3v;
            out_res[(size_t)g1 * LATENTS + l] = so[1][0] + b3v;
            atomicAdd(&out_lad[g0], __logf(fabsf(sd[0][0]) + FEPS));
            atomicAdd(&out_lad[g1], __logf(fabsf(sd[1][0]) + FEPS));
        }
    }
}

extern "C" void kernel_launch(void* const* d_in, const int* in_sizes, int n_in,
                              void* d_out, int out_size, void* d_ws, size_t ws_size,
                              hipStream_t stream)
{
    const float* x  = (const float*)d_in[0];
    const float* W0 = (const float*)d_in[1];
    const float* b0 = (const float*)d_in[2];
    const float* W1 = (const float*)d_in[3];
    const float* b1 = (const float*)d_in[4];
    const float* W2 = (const float*)d_in[5];
    const float* b2 = (const float*)d_in[6];
    const float* W3 = (const float*)d_in[7];
    const float* b3 = (const float*)d_in[8];

    const int B = in_sizes[0] / (LATENTS * IN_DIM);  // 8192
    float* out_res = (float*)d_out;
    float* out_lad = out_res + (size_t)B * LATENTS;
    char*  wsp     = (char*)d_ws;   // 64*52KB frags + 16KB w65 = 3.27 MB

    lad_init_kernel<<<dim3((B + 255) / 256), dim3(256), 0, stream>>>(out_lad, B);
    w_prep_kernel<<<dim3(256), dim3(64), 0, stream>>>(W0, W1, W2, W3, wsp);
    flow_mfma_kernel<<<dim3(B / RPB, LATENTS), dim3(256), 0, stream>>>(
        x, b0, b1, b2, b3, wsp, out_res, out_lad);
}